// Round 10
// baseline (39.108 us; speedup 1.0000x reference)
//
#include <hip/hip_runtime.h>

#define N_IMG 8
#define CIN   128
#define H_IN  56
#define W_IN  56
#define COUT  128
#define HW    3136
#define TROWS 9                        // tile rows [ro0-3, ro0+5], 2 output rows
#define TILE_B (TROWS * 56 * 256)      // 129024
#define PMC_OFF TILE_B                 // int[1152]
#define PMW_OFF (TILE_B + 4608)        // ushort4[1152]
#define SMEM_TOTAL (TILE_B + 4608 + 9216)   // 142848 <= 163840

typedef __attribute__((ext_vector_type(8))) short short8;
typedef __attribute__((ext_vector_type(4))) float f32x4;
typedef _Float16 h8 __attribute__((ext_vector_type(8)));

__device__ __forceinline__ unsigned short hb(float f) {
    _Float16 h = (_Float16)f;
    return __builtin_bit_cast(unsigned short, h);
}
__device__ __forceinline__ h8 splat8(unsigned short b) {
    _Float16 s = __builtin_bit_cast(_Float16, b);
    return (h8){s, s, s, s, s, s, s, s};
}
__device__ __forceinline__ void gload16(const void* g, void* l) {
    __builtin_amdgcn_global_load_lds(
        (const __attribute__((address_space(1))) unsigned int*)g,
        (__attribute__((address_space(3))) unsigned int*)l, 16, 0, 0);
}

// blocks 0..783: x (N,C,H,W) f32 -> xt (N,H,W,C) f16
// blocks 784..855: weight -> wr[tap][kc4][f][lane][8] f16 (B-fragment-linear)
__global__ __launch_bounds__(256) void prep_kernel(const float* __restrict__ x,
                                                   const float* __restrict__ w,
                                                   unsigned short* __restrict__ xt,
                                                   unsigned short* __restrict__ wr) {
    int b = blockIdx.x;
    int tid = threadIdx.x;
    if (b < 784) {
        int c = tid & 127;
        int half = tid >> 7;
        int n = b / 98;
        int hw0 = (b - n * 98) * 32 + half * 16;
        const float* xp = x + ((size_t)(n * CIN + c)) * HW + hw0;
        unsigned short* op = xt + ((size_t)n * HW + hw0) * CIN + c;
#pragma unroll
        for (int r = 0; r < 16; ++r) op[r * CIN] = hb(xp[r]);
    } else {
        int G = (b - 784) * 256 + tid;          // 0..18431 = 36*8*64
        int lane = G & 63;
        int f = (G >> 6) & 7;
        int kc4 = (G >> 9) & 3;
        int tap = G >> 11;
        int cout = f * 16 + (lane & 15);
        int ch = kc4 * 32 + (lane >> 4) * 8;
        short8 v;
#pragma unroll
        for (int j = 0; j < 8; ++j)
            v[j] = (short)hb(w[((size_t)cout * CIN + ch + j) * 9 + tap]);
        *(short8*)(wr + (size_t)G * 8) = v;
    }
}

__global__ __launch_bounds__(768, 3) void deform_main(
    const float* __restrict__ offset, const float* __restrict__ x2,
    const float* __restrict__ bias, const unsigned short* __restrict__ xt,
    const unsigned short* __restrict__ wr, float* __restrict__ out)
{
    extern __shared__ char smem[];
    int*     pmc = (int*)(smem + PMC_OFF);
    ushort4* pmw = (ushort4*)(smem + PMW_OFF);

    int tid = threadIdx.x;
    int orig = blockIdx.x;                 // 224 = 8 images * 28 row-pairs
    int n   = orig & 7;                    // one image per XCD
    int ro0 = (orig >> 3) * 2;             // first of 2 output rows

    const char* xim = (const char*)(xt + (size_t)n * HW * CIN);

    // ---- stage 9x56x128ch f16 tile, swizzled (slot = chunk ^ (p&15)) ----
#pragma unroll
    for (int s = 0; s < 11; ++s) {
        int d = s * 12288 + tid * 16;
        if (d < TILE_B) {
            int p = d >> 8;                // tile-linear pixel 0..503
            int tr = p / 56;
            int tx = p - tr * 56;
            int gy = min(max(ro0 - 3 + tr, 0), 55);
            int c  = ((d >> 4) & 15) ^ (p & 15);
            gload16(xim + (((gy * 56 + tx) << 8) + (c << 4)), smem + d);
        }
    }

    // ---- bilinear params: 1152 = 2 rows x 9 taps x 64 px ----
    for (int e = tid; e < 1152; e += 768) {
        int r = (e >= 576) ? 1 : 0;
        int e2 = e - r * 576;
        int tap = e2 >> 6;
        int px  = e2 & 63;
        int wo  = min(px, 55);
        int hor = ro0 + r;
        const float* offp = offset + ((size_t)n * 18 + tap * 2) * HW + hor * 56 + wo;
        float offy = offp[0];
        float offx = offp[HW];
        int ki = tap / 3;
        int kj = tap - ki * 3;
        float py  = (float)(hor - 1 + ki) + offy;
        float pxf = (float)(wo - 1 + kj) + offx;
        float y0f = floorf(py), x0f = floorf(pxf);
        float wy = py - y0f, wx = pxf - x0f;
        int y0 = (int)y0f, x0 = (int)x0f;
        int y1 = y0 + 1, x1 = x0 + 1;
        bool vy0 = (y0 >= 0) && (y0 < H_IN);
        bool vy1 = (y1 >= 0) && (y1 < H_IN);
        bool vx0 = (x0 >= 0) && (x0 < W_IN);
        bool vx1 = (x1 >= 0) && (x1 < W_IN);
        int cy0 = min(max(y0, 0), 55), cy1 = min(max(y1, 0), 55);
        int cx0 = min(max(x0, 0), 55), cx1 = min(max(x1, 0), 55);
        int f0 = (y0 < ro0 - 3 || y0 > ro0 + 5) ? 1 : 0;   // outside 9-row tile
        int f1 = (y1 < ro0 - 3 || y1 > ro0 + 5) ? 1 : 0;
        pmc[e] = cy0 | (cy1 << 6) | (cx0 << 12) | (cx1 << 18) | (f0 << 24) | (f1 << 25);
        ushort4 wp;
        wp.x = hb((vy0 && vx0) ? (1.f - wy) * (1.f - wx) : 0.f);
        wp.y = hb((vy0 && vx1) ? (1.f - wy) * wx : 0.f);
        wp.z = hb((vy1 && vx0) ? wy * (1.f - wx) : 0.f);
        wp.w = hb((vy1 && vx1) ? wy * wx : 0.f);
        pmw[e] = wp;
    }
    __syncthreads();   // tile + params visible; loop is barrier-free

    int lane = tid & 63;
    int w12 = tid >> 6;            // 12 waves = 3 kg x 4 mt
    int mt = w12 & 3;              // 32-px slot block
    int kg = w12 >> 2;             // tap-third: taps kg*3 .. kg*3+2
    int llo = lane & 15, lhi = lane >> 4;
    int slot0 = mt * 32 + llo;     // px-frag 0
    int slot1 = slot0 + 16;        // px-frag 1
    int eb0 = (slot0 >> 6) * 576 + (slot0 & 63);
    int eb1 = (slot1 >> 6) * 576 + (slot1 & 63);
    const char* wrb = (const char*)wr;

    f32x4 acc[2][8] = {};

    for (int t3 = 0; t3 < 3; ++t3) {
        int tap = kg * 3 + t3;
        int cw0 = pmc[eb0 + tap * 64];
        int cw1 = pmc[eb1 + tap * 64];
        ushort4 wp0 = pmw[eb0 + tap * 64];
        ushort4 wp1 = pmw[eb1 + tap * 64];
        // decode q0
        int a_cy0 = cw0 & 63, a_cy1 = (cw0 >> 6) & 63;
        int a_cx0 = (cw0 >> 12) & 63, a_cx1 = (cw0 >> 18) & 63;
        int a_tr0 = min(max(a_cy0 + 3 - ro0, 0), TROWS - 1);
        int a_tr1 = min(max(a_cy1 + 3 - ro0, 0), TROWS - 1);
        int a_p00 = a_tr0 * 56 + a_cx0, a_p01 = a_tr0 * 56 + a_cx1;
        int a_p10 = a_tr1 * 56 + a_cx0, a_p11 = a_tr1 * 56 + a_cx1;
        bool a_b0 = ((cw0 >> 24) & 1) && (wp0.x != 0);
        bool a_b1 = ((cw0 >> 24) & 1) && (wp0.y != 0);
        bool a_b2 = ((cw0 >> 25) & 1) && (wp0.z != 0);
        bool a_b3 = ((cw0 >> 25) & 1) && (wp0.w != 0);
        bool a_fb = __any(a_b0 | a_b1 | a_b2 | a_b3);
        // decode q1
        int c_cy0 = cw1 & 63, c_cy1 = (cw1 >> 6) & 63;
        int c_cx0 = (cw1 >> 12) & 63, c_cx1 = (cw1 >> 18) & 63;
        int c_tr0 = min(max(c_cy0 + 3 - ro0, 0), TROWS - 1);
        int c_tr1 = min(max(c_cy1 + 3 - ro0, 0), TROWS - 1);
        int c_p00 = c_tr0 * 56 + c_cx0, c_p01 = c_tr0 * 56 + c_cx1;
        int c_p10 = c_tr1 * 56 + c_cx0, c_p11 = c_tr1 * 56 + c_cx1;
        bool c_b0 = ((cw1 >> 24) & 1) && (wp1.x != 0);
        bool c_b1 = ((cw1 >> 24) & 1) && (wp1.y != 0);
        bool c_b2 = ((cw1 >> 25) & 1) && (wp1.z != 0);
        bool c_b3 = ((cw1 >> 25) & 1) && (wp1.w != 0);
        bool c_fb = __any(c_b0 | c_b1 | c_b2 | c_b3);

        const char* bb = wrb + (size_t)tap * 32768 + lane * 16;

#pragma unroll
        for (int kc = 0; kc < 4; ++kc) {
            // B fragments first: issue early, consumed by MFMAs after interp
            h8 bf[8];
#pragma unroll
            for (int f = 0; f < 8; ++f)
                bf[f] = *(const h8*)(bb + kc * 8192 + f * 1024);

            int cbase = kc * 4 + lhi;   // 16B chunk within 256B px block

            h8 g0 = *(const h8*)(smem + (a_p00 << 8) + ((cbase ^ (a_p00 & 15)) << 4));
            h8 g1 = *(const h8*)(smem + (a_p01 << 8) + ((cbase ^ (a_p01 & 15)) << 4));
            h8 g2 = *(const h8*)(smem + (a_p10 << 8) + ((cbase ^ (a_p10 & 15)) << 4));
            h8 g3 = *(const h8*)(smem + (a_p11 << 8) + ((cbase ^ (a_p11 & 15)) << 4));
            if (a_fb) {
                if (a_b0) g0 = *(const h8*)(xim + ((size_t)(a_cy0 * 56 + a_cx0) << 8) + (cbase << 4));
                if (a_b1) g1 = *(const h8*)(xim + ((size_t)(a_cy0 * 56 + a_cx1) << 8) + (cbase << 4));
                if (a_b2) g2 = *(const h8*)(xim + ((size_t)(a_cy1 * 56 + a_cx0) << 8) + (cbase << 4));
                if (a_b3) g3 = *(const h8*)(xim + ((size_t)(a_cy1 * 56 + a_cx1) << 8) + (cbase << 4));
            }
            h8 a0 = g0 * splat8(wp0.x) + g1 * splat8(wp0.y)
                  + g2 * splat8(wp0.z) + g3 * splat8(wp0.w);

            h8 h0 = *(const h8*)(smem + (c_p00 << 8) + ((cbase ^ (c_p00 & 15)) << 4));
            h8 h1 = *(const h8*)(smem + (c_p01 << 8) + ((cbase ^ (c_p01 & 15)) << 4));
            h8 h2 = *(const h8*)(smem + (c_p10 << 8) + ((cbase ^ (c_p10 & 15)) << 4));
            h8 h3 = *(const h8*)(smem + (c_p11 << 8) + ((cbase ^ (c_p11 & 15)) << 4));
            if (c_fb) {
                if (c_b0) h0 = *(const h8*)(xim + ((size_t)(c_cy0 * 56 + c_cx0) << 8) + (cbase << 4));
                if (c_b1) h1 = *(const h8*)(xim + ((size_t)(c_cy0 * 56 + c_cx1) << 8) + (cbase << 4));
                if (c_b2) h2 = *(const h8*)(xim + ((size_t)(c_cy1 * 56 + c_cx0) << 8) + (cbase << 4));
                if (c_b3) h3 = *(const h8*)(xim + ((size_t)(c_cy1 * 56 + c_cx1) << 8) + (cbase << 4));
            }
            h8 a1 = h0 * splat8(wp1.x) + h1 * splat8(wp1.y)
                  + h2 * splat8(wp1.z) + h3 * splat8(wp1.w);

#pragma unroll
            for (int f = 0; f < 8; ++f) {
                acc[0][f] = __builtin_amdgcn_mfma_f32_16x16x32_f16(a0, bf[f], acc[0][f], 0, 0, 0);
                acc[1][f] = __builtin_amdgcn_mfma_f32_16x16x32_f16(a1, bf[f], acc[1][f], 0, 0, 0);
            }
        }
    }

    // ---- split-K (kg 1,2 -> kg 0) via LDS (tile region reused), then epilogue ----
    __syncthreads();                       // all tile reads done WG-wide
    if (kg > 0) {
        char* red = smem + (size_t)(kg - 1) * 65536;
#pragma unroll
        for (int q = 0; q < 2; ++q)
#pragma unroll
            for (int f = 0; f < 8; ++f)
                *(f32x4*)(red + ((((mt * 2 + q) * 8 + f) << 10) + (lane << 4))) = acc[q][f];
    }
    __syncthreads();
    if (kg == 0) {
#pragma unroll
        for (int q = 0; q < 2; ++q)
#pragma unroll
            for (int f = 0; f < 8; ++f) {
                size_t ro = (((mt * 2 + q) * 8 + f) << 10) + (lane << 4);
                acc[q][f] += *(const f32x4*)(smem + ro);
                acc[q][f] += *(const f32x4*)(smem + 65536 + ro);
            }

#pragma unroll
        for (int q = 0; q < 2; ++q) {
            int slotq = mt * 32 + q * 16 + lhi * 4;   // 4 consecutive px slots
            int srow = slotq >> 6;
            int wo4 = slotq & 63;
            if (wo4 < 56) {
#pragma unroll
                for (int f = 0; f < 8; ++f) {
                    int cout = f * 16 + llo;
                    float bb = bias[cout];
                    size_t off = ((size_t)(n * COUT + cout)) * HW + (ro0 + srow) * 56 + wo4;
                    f32x4 xv = *(const f32x4*)(x2 + off);
                    f32x4 o;
#pragma unroll
                    for (int r = 0; r < 4; ++r) {
                        float v = acc[q][f][r] + bb + xv[r];
                        o[r] = v > 0.f ? v : 0.f;
                    }
                    *(f32x4*)(out + off) = o;
                }
            }
        }
    }
}

extern "C" void kernel_launch(void* const* d_in, const int* in_sizes, int n_in,
                              void* d_out, int out_size, void* d_ws, size_t ws_size,
                              hipStream_t stream) {
    const float* x      = (const float*)d_in[0];
    const float* offset = (const float*)d_in[1];
    const float* weight = (const float*)d_in[2];
    const float* bias   = (const float*)d_in[3];
    const float* x2     = (const float*)d_in[4];
    float* out = (float*)d_out;

    unsigned short* xt = (unsigned short*)d_ws;                       // 6,422,528 B
    unsigned short* wr = (unsigned short*)((char*)d_ws + 6422528ULL); // 294,912 B

    hipFuncSetAttribute((const void*)deform_main,
                        hipFuncAttributeMaxDynamicSharedMemorySize, SMEM_TOTAL);
    prep_kernel<<<856, 256, 0, stream>>>(x, weight, xt, wr);
    deform_main<<<224, 768, SMEM_TOTAL, stream>>>(offset, x2, bias, xt, wr, out);
}

// Round 11
// 33.591 us; speedup vs baseline: 1.1642x; 1.1642x over previous
//
#include <hip/hip_runtime.h>

#define N_IMG 8
#define CIN   128
#define H_IN  56
#define W_IN  56
#define COUT  128
#define HW    3136
#define TROWS 9                        // tile rows [ro0-3, ro0+5], 2 output rows
#define TILE_B (TROWS * 56 * 256)      // 129024
#define PMC_OFF TILE_B                 // int[1152]
#define PMW_OFF (TILE_B + 4608)        // ushort4[1152]
#define SMEM_TOTAL (TILE_B + 4608 + 9216)   // 142848 <= 163840

typedef __attribute__((ext_vector_type(8))) short short8;
typedef __attribute__((ext_vector_type(4))) float f32x4;
typedef _Float16 h8 __attribute__((ext_vector_type(8)));

__device__ __forceinline__ unsigned short hb(float f) {
    _Float16 h = (_Float16)f;
    return __builtin_bit_cast(unsigned short, h);
}
__device__ __forceinline__ h8 splat8(unsigned short b) {
    _Float16 s = __builtin_bit_cast(_Float16, b);
    return (h8){s, s, s, s, s, s, s, s};
}
__device__ __forceinline__ void gload16(const void* g, void* l) {
    __builtin_amdgcn_global_load_lds(
        (const __attribute__((address_space(1))) unsigned int*)g,
        (__attribute__((address_space(3))) unsigned int*)l, 16, 0, 0);
}

// blocks 0..783: x (N,C,H,W) f32 -> xt (N,H,W,C) f16
// blocks 784..855: weight -> wr[tap][kc4][f][lane][8] f16 (B-fragment-linear)
__global__ __launch_bounds__(256) void prep_kernel(const float* __restrict__ x,
                                                   const float* __restrict__ w,
                                                   unsigned short* __restrict__ xt,
                                                   unsigned short* __restrict__ wr) {
    int b = blockIdx.x;
    int tid = threadIdx.x;
    if (b < 784) {
        int c = tid & 127;
        int half = tid >> 7;
        int n = b / 98;
        int hw0 = (b - n * 98) * 32 + half * 16;
        const float* xp = x + ((size_t)(n * CIN + c)) * HW + hw0;
        unsigned short* op = xt + ((size_t)n * HW + hw0) * CIN + c;
#pragma unroll
        for (int r = 0; r < 16; ++r) op[r * CIN] = hb(xp[r]);
    } else {
        int G = (b - 784) * 256 + tid;          // 0..18431 = 36*8*64
        int lane = G & 63;
        int f = (G >> 6) & 7;
        int kc4 = (G >> 9) & 3;
        int tap = G >> 11;
        int cout = f * 16 + (lane & 15);
        int ch = kc4 * 32 + (lane >> 4) * 8;
        short8 v;
#pragma unroll
        for (int j = 0; j < 8; ++j)
            v[j] = (short)hb(w[((size_t)cout * CIN + ch + j) * 9 + tap]);
        *(short8*)(wr + (size_t)G * 8) = v;
    }
}

__global__ __launch_bounds__(512, 2) void deform_main(
    const float* __restrict__ offset, const float* __restrict__ x2,
    const float* __restrict__ bias, const unsigned short* __restrict__ xt,
    const unsigned short* __restrict__ wr, float* __restrict__ out)
{
    extern __shared__ char smem[];
    int*     pmc = (int*)(smem + PMC_OFF);
    ushort4* pmw = (ushort4*)(smem + PMW_OFF);

    int tid = threadIdx.x;
    int orig = blockIdx.x;                 // 224 = 8 images * 28 row-pairs
    int n   = orig & 7;                    // one image per XCD
    int ro0 = (orig >> 3) * 2;             // first of 2 output rows

    const char* xim = (const char*)(xt + (size_t)n * HW * CIN);

    // ---- stage 9x56x128ch f16 tile, swizzled (slot = chunk ^ (p&15)) ----
#pragma unroll
    for (int s = 0; s < 16; ++s) {
        int d = s * 8192 + tid * 16;
        if (d < TILE_B) {
            int p = d >> 8;                // tile-linear pixel 0..503
            int tr = p / 56;
            int tx = p - tr * 56;
            int gy = min(max(ro0 - 3 + tr, 0), 55);
            int c  = ((d >> 4) & 15) ^ (p & 15);
            gload16(xim + (((gy * 56 + tx) << 8) + (c << 4)), smem + d);
        }
    }

    // ---- bilinear params: 1152 = 2 rows x 9 taps x 64 px ----
    for (int e = tid; e < 1152; e += 512) {
        int r = (e >= 576) ? 1 : 0;
        int e2 = e - r * 576;
        int tap = e2 >> 6;
        int px  = e2 & 63;
        int wo  = min(px, 55);
        int hor = ro0 + r;
        const float* offp = offset + ((size_t)n * 18 + tap * 2) * HW + hor * 56 + wo;
        float offy = offp[0];
        float offx = offp[HW];
        int ki = tap / 3;
        int kj = tap - ki * 3;
        float py  = (float)(hor - 1 + ki) + offy;
        float pxf = (float)(wo - 1 + kj) + offx;
        float y0f = floorf(py), x0f = floorf(pxf);
        float wy = py - y0f, wx = pxf - x0f;
        int y0 = (int)y0f, x0 = (int)x0f;
        int y1 = y0 + 1, x1 = x0 + 1;
        bool vy0 = (y0 >= 0) && (y0 < H_IN);
        bool vy1 = (y1 >= 0) && (y1 < H_IN);
        bool vx0 = (x0 >= 0) && (x0 < W_IN);
        bool vx1 = (x1 >= 0) && (x1 < W_IN);
        int cy0 = min(max(y0, 0), 55), cy1 = min(max(y1, 0), 55);
        int cx0 = min(max(x0, 0), 55), cx1 = min(max(x1, 0), 55);
        int f0 = (y0 < ro0 - 3 || y0 > ro0 + 5) ? 1 : 0;   // outside 9-row tile
        int f1 = (y1 < ro0 - 3 || y1 > ro0 + 5) ? 1 : 0;
        pmc[e] = cy0 | (cy1 << 6) | (cx0 << 12) | (cx1 << 18) | (f0 << 24) | (f1 << 25);
        ushort4 wp;
        wp.x = hb((vy0 && vx0) ? (1.f - wy) * (1.f - wx) : 0.f);
        wp.y = hb((vy0 && vx1) ? (1.f - wy) * wx : 0.f);
        wp.z = hb((vy1 && vx0) ? wy * (1.f - wx) : 0.f);
        wp.w = hb((vy1 && vx1) ? wy * wx : 0.f);
        pmw[e] = wp;
    }
    __syncthreads();   // tile + params visible; loop is barrier-free

    int lane = tid & 63;
    int w8 = tid >> 6;             // 8 waves = 2 kg x 4 mt
    int kg = w8 & 1;               // 64-channel half
    int mt = w8 >> 1;              // 32-px slot block (m=2)
    int llo = lane & 15, lhi = lane >> 4;
    int slot0 = mt * 32 + llo;     // px-frag 0
    int slot1 = slot0 + 16;        // px-frag 1
    int eb0 = (slot0 >> 6) * 576 + (slot0 & 63);
    int eb1 = (slot1 >> 6) * 576 + (slot1 & 63);
    const char* wrb = (const char*)wr;

    f32x4 acc[2][8] = {};

    for (int tap = 0; tap < 9; ++tap) {
        int cw0 = pmc[eb0 + tap * 64];
        int cw1 = pmc[eb1 + tap * 64];
        ushort4 wp0 = pmw[eb0 + tap * 64];
        ushort4 wp1 = pmw[eb1 + tap * 64];
        // decode q0
        int a_cy0 = cw0 & 63, a_cy1 = (cw0 >> 6) & 63;
        int a_cx0 = (cw0 >> 12) & 63, a_cx1 = (cw0 >> 18) & 63;
        int a_tr0 = min(max(a_cy0 + 3 - ro0, 0), TROWS - 1);
        int a_tr1 = min(max(a_cy1 + 3 - ro0, 0), TROWS - 1);
        int a_p00 = a_tr0 * 56 + a_cx0, a_p01 = a_tr0 * 56 + a_cx1;
        int a_p10 = a_tr1 * 56 + a_cx0, a_p11 = a_tr1 * 56 + a_cx1;
        bool a_b0 = ((cw0 >> 24) & 1) && (wp0.x != 0);
        bool a_b1 = ((cw0 >> 24) & 1) && (wp0.y != 0);
        bool a_b2 = ((cw0 >> 25) & 1) && (wp0.z != 0);
        bool a_b3 = ((cw0 >> 25) & 1) && (wp0.w != 0);
        bool a_fb = __any(a_b0 | a_b1 | a_b2 | a_b3);
        // decode q1
        int c_cy0 = cw1 & 63, c_cy1 = (cw1 >> 6) & 63;
        int c_cx0 = (cw1 >> 12) & 63, c_cx1 = (cw1 >> 18) & 63;
        int c_tr0 = min(max(c_cy0 + 3 - ro0, 0), TROWS - 1);
        int c_tr1 = min(max(c_cy1 + 3 - ro0, 0), TROWS - 1);
        int c_p00 = c_tr0 * 56 + c_cx0, c_p01 = c_tr0 * 56 + c_cx1;
        int c_p10 = c_tr1 * 56 + c_cx0, c_p11 = c_tr1 * 56 + c_cx1;
        bool c_b0 = ((cw1 >> 24) & 1) && (wp1.x != 0);
        bool c_b1 = ((cw1 >> 24) & 1) && (wp1.y != 0);
        bool c_b2 = ((cw1 >> 25) & 1) && (wp1.z != 0);
        bool c_b3 = ((cw1 >> 25) & 1) && (wp1.w != 0);
        bool c_fb = __any(c_b0 | c_b1 | c_b2 | c_b3);

#pragma unroll
        for (int kc = 0; kc < 2; ++kc) {
            int kc4 = kg * 2 + kc;
            // batch-issue B fragments first: in flight across gather+interp
            const char* bb = wrb + (size_t)((tap * 4 + kc4) * 8) * 1024 + lane * 16;
            h8 bf[8];
#pragma unroll
            for (int f = 0; f < 8; ++f)
                bf[f] = *(const h8*)(bb + f * 1024);

            int cbase = kc4 * 4 + lhi;   // 16B chunk within 256B px block

            h8 g0 = *(const h8*)(smem + (a_p00 << 8) + ((cbase ^ (a_p00 & 15)) << 4));
            h8 g1 = *(const h8*)(smem + (a_p01 << 8) + ((cbase ^ (a_p01 & 15)) << 4));
            h8 g2 = *(const h8*)(smem + (a_p10 << 8) + ((cbase ^ (a_p10 & 15)) << 4));
            h8 g3 = *(const h8*)(smem + (a_p11 << 8) + ((cbase ^ (a_p11 & 15)) << 4));
            if (a_fb) {
                if (a_b0) g0 = *(const h8*)(xim + ((size_t)(a_cy0 * 56 + a_cx0) << 8) + (cbase << 4));
                if (a_b1) g1 = *(const h8*)(xim + ((size_t)(a_cy0 * 56 + a_cx1) << 8) + (cbase << 4));
                if (a_b2) g2 = *(const h8*)(xim + ((size_t)(a_cy1 * 56 + a_cx0) << 8) + (cbase << 4));
                if (a_b3) g3 = *(const h8*)(xim + ((size_t)(a_cy1 * 56 + a_cx1) << 8) + (cbase << 4));
            }
            h8 a0 = g0 * splat8(wp0.x) + g1 * splat8(wp0.y)
                  + g2 * splat8(wp0.z) + g3 * splat8(wp0.w);

            h8 h0 = *(const h8*)(smem + (c_p00 << 8) + ((cbase ^ (c_p00 & 15)) << 4));
            h8 h1 = *(const h8*)(smem + (c_p01 << 8) + ((cbase ^ (c_p01 & 15)) << 4));
            h8 h2 = *(const h8*)(smem + (c_p10 << 8) + ((cbase ^ (c_p10 & 15)) << 4));
            h8 h3 = *(const h8*)(smem + (c_p11 << 8) + ((cbase ^ (c_p11 & 15)) << 4));
            if (c_fb) {
                if (c_b0) h0 = *(const h8*)(xim + ((size_t)(c_cy0 * 56 + c_cx0) << 8) + (cbase << 4));
                if (c_b1) h1 = *(const h8*)(xim + ((size_t)(c_cy0 * 56 + c_cx1) << 8) + (cbase << 4));
                if (c_b2) h2 = *(const h8*)(xim + ((size_t)(c_cy1 * 56 + c_cx0) << 8) + (cbase << 4));
                if (c_b3) h3 = *(const h8*)(xim + ((size_t)(c_cy1 * 56 + c_cx1) << 8) + (cbase << 4));
            }
            h8 a1 = h0 * splat8(wp1.x) + h1 * splat8(wp1.y)
                  + h2 * splat8(wp1.z) + h3 * splat8(wp1.w);

#pragma unroll
            for (int f = 0; f < 8; ++f) {
                acc[0][f] = __builtin_amdgcn_mfma_f32_16x16x32_f16(a0, bf[f], acc[0][f], 0, 0, 0);
                acc[1][f] = __builtin_amdgcn_mfma_f32_16x16x32_f16(a1, bf[f], acc[1][f], 0, 0, 0);
            }
        }
    }

    // ---- split-K (kg=1 -> kg=0) via LDS (tile region reused), then epilogue ----
    __syncthreads();                       // all tile reads done WG-wide
    if (kg == 1) {
#pragma unroll
        for (int q = 0; q < 2; ++q)
#pragma unroll
            for (int f = 0; f < 8; ++f)
                *(f32x4*)(smem + ((((mt * 2 + q) * 8 + f) << 10) + (lane << 4))) = acc[q][f];
    }
    __syncthreads();
    if (kg == 0) {
#pragma unroll
        for (int q = 0; q < 2; ++q)
#pragma unroll
            for (int f = 0; f < 8; ++f) {
                size_t ro = (((mt * 2 + q) * 8 + f) << 10) + (lane << 4);
                acc[q][f] += *(const f32x4*)(smem + ro);
            }

#pragma unroll
        for (int q = 0; q < 2; ++q) {
            int slotq = mt * 32 + q * 16 + lhi * 4;   // 4 consecutive px slots
            int srow = slotq >> 6;
            int wo4 = slotq & 63;
            if (wo4 < 56) {
#pragma unroll
                for (int f = 0; f < 8; ++f) {
                    int cout = f * 16 + llo;
                    float bb = bias[cout];
                    size_t off = ((size_t)(n * COUT + cout)) * HW + (ro0 + srow) * 56 + wo4;
                    f32x4 xv = *(const f32x4*)(x2 + off);
                    f32x4 o;
#pragma unroll
                    for (int r = 0; r < 4; ++r) {
                        float v = acc[q][f][r] + bb + xv[r];
                        o[r] = v > 0.f ? v : 0.f;
                    }
                    *(f32x4*)(out + off) = o;
                }
            }
        }
    }
}

extern "C" void kernel_launch(void* const* d_in, const int* in_sizes, int n_in,
                              void* d_out, int out_size, void* d_ws, size_t ws_size,
                              hipStream_t stream) {
    const float* x      = (const float*)d_in[0];
    const float* offset = (const float*)d_in[1];
    const float* weight = (const float*)d_in[2];
    const float* bias   = (const float*)d_in[3];
    const float* x2     = (const float*)d_in[4];
    float* out = (float*)d_out;

    unsigned short* xt = (unsigned short*)d_ws;                       // 6,422,528 B
    unsigned short* wr = (unsigned short*)((char*)d_ws + 6422528ULL); // 294,912 B

    hipFuncSetAttribute((const void*)deform_main,
                        hipFuncAttributeMaxDynamicSharedMemorySize, SMEM_TOTAL);
    prep_kernel<<<856, 256, 0, stream>>>(x, weight, xt, wr);
    deform_main<<<224, 512, SMEM_TOTAL, stream>>>(offset, x2, bias, xt, wr, out);
}